// Round 7
// baseline (202.125 us; speedup 1.0000x reference)
//
#include <hip/hip_runtime.h>
#include <math.h>

#define D 64
#define S 4

// ---------------- workspace layout (float offsets) ----------------
#define WS_KEYS 0      // keys[S][D]
#define WS_ST   256    // st_norm[S]
#define WS_SUMS 260    // uw_sums[S] (atomic, zeroed each launch)
#define WS_LW   264    // last_writer[S] (int, -1 init)
#define WS_OUT1 272    // out1[D] (16B aligned)
#define WS_WQT  512    // WqT[k][d] = Wq[d][k], 64x64

__global__ void k_prep(const float* __restrict__ slots,
                       const float* __restrict__ ss,
                       const float* __restrict__ Wk,
                       const float* __restrict__ bk,
                       const float* __restrict__ Wq,
                       float* __restrict__ ws) {
  int d = threadIdx.x;  // 64 threads
  __shared__ float sl[S][D];
  for (int s = 0; s < S; ++s) sl[s][d] = slots[s * D + d];
  __syncthreads();
  float bkd = bk[d];
  for (int s = 0; s < S; ++s) {
    float acc = bkd;
    for (int k = 0; k < D; ++k) acc = fmaf(sl[s][k], Wk[d * D + k], acc);
    ws[WS_KEYS + s * D + d] = tanhf(acc);
  }
  // transpose Wq into ws: WqT[k][d] = Wq[d][k]
  for (int k = 0; k < D; ++k) ws[WS_WQT + k * D + d] = Wq[d * D + k];
  if (d < S) {
    ws[WS_SUMS + d] = 0.f;
    ((int*)ws)[WS_LW + d] = -1;
  }
  if (d == 0) {
    float st[S]; float tot = 0.f;
    for (int s = 0; s < S; ++s) {
      float x = ss[s];
      float sp = log1pf(expf(-fabsf(x))) + fmaxf(x, 0.f);  // softplus
      st[s] = sp; tot += sp;
    }
    for (int s = 0; s < S; ++s) ws[WS_ST + s] = st[s] / tot;
  }
}

// NOTE: macro params must not collide with .x/.y/.z/.w member names
#define FMA4(A_, XS_, W_) \
  A_.x = fmaf(XS_, W_.x, A_.x); A_.y = fmaf(XS_, W_.y, A_.y); \
  A_.z = fmaf(XS_, W_.z, A_.z); A_.w = fmaf(XS_, W_.w, A_.w);

#define TANH1(V_) fmaf(-2.f, __builtin_amdgcn_rcpf(__expf(2.f * (V_)) + 1.f), 1.f)
#define TANH4(A_) { A_.x = TANH1(A_.x); A_.y = TANH1(A_.y); A_.z = TANH1(A_.z); A_.w = TANH1(A_.w); }

#define DOT4ACC(P_, A_, K_) \
  P_ = fmaf(A_.x, K_.x, P_); P_ = fmaf(A_.y, K_.y, P_); \
  P_ = fmaf(A_.z, K_.z, P_); P_ = fmaf(A_.w, K_.w, P_);

// one k-scalar step: broadcast XS_ against the full 64-wide W row (16 f4)
#define KSTEP(WP_, XS_) { \
  FMA4(A0,  XS_, WP_[0])  FMA4(A1,  XS_, WP_[1])  FMA4(A2,  XS_, WP_[2])  FMA4(A3,  XS_, WP_[3])  \
  FMA4(A4,  XS_, WP_[4])  FMA4(A5,  XS_, WP_[5])  FMA4(A6,  XS_, WP_[6])  FMA4(A7,  XS_, WP_[7])  \
  FMA4(A8,  XS_, WP_[8])  FMA4(A9,  XS_, WP_[9])  FMA4(A10, XS_, WP_[10]) FMA4(A11, XS_, WP_[11]) \
  FMA4(A12, XS_, WP_[12]) FMA4(A13, XS_, WP_[13]) FMA4(A14, XS_, WP_[14]) FMA4(A15, XS_, WP_[15]) }

// 1 row/lane; item tile (256 rows) staged coalesced into LDS; lane reads its
// own row from LDS (1 ds_read_b128 per 64 FMA). W/keys/bq via uniform s_load.
// Rows padded to 17 float4 -> per-wave bank footprint uniform (min-cycle).
// B % 256 == 0 -> no tail guards in compute.
__launch_bounds__(256, 1)
__global__ void k_main(const float* __restrict__ item,
                       const float* __restrict__ wqt,   // ws+WS_WQT
                       const float* __restrict__ keys,  // ws+WS_KEYS
                       const float* __restrict__ st4,   // ws+WS_ST
                       const float* __restrict__ bq,
                       float* red,                      // ws (atomics)
                       float* __restrict__ slot_weights,
                       float* __restrict__ selected,
                       int B) {
  __shared__ float4 xs4[256 * 17];   // 256 rows x 17 f4 (68-dword pitch) 69.6KB
  __shared__ float  red_sum[4][S];
  __shared__ int    red_lw[4][S];

  int t = threadIdx.x;
  long b = (long)blockIdx.x * 256 + t;

  // ---- coalesced staging: 4096 f4, 16 per thread ----
  {
    const float4* gsrc = (const float4*)item + ((long)blockIdx.x << 12);
    #pragma unroll
    for (int i = 0; i < 16; ++i) {
      int idx = t + 256 * i;
      int r = idx >> 4, c4 = idx & 15;
      xs4[r * 17 + c4] = gsrc[idx];
    }
  }
  __syncthreads();

  const float4* bq4 = (const float4*)bq;
  float4 A0  = bq4[0],  A1  = bq4[1],  A2  = bq4[2],  A3  = bq4[3];
  float4 A4  = bq4[4],  A5  = bq4[5],  A6  = bq4[6],  A7  = bq4[7];
  float4 A8  = bq4[8],  A9  = bq4[9],  A10 = bq4[10], A11 = bq4[11];
  float4 A12 = bq4[12], A13 = bq4[13], A14 = bq4[14], A15 = bq4[15];

  const float4* wr = (const float4*)wqt;     // wr[k*16 + dq], uniform
  const float4* xrow = xs4 + t * 17;         // this lane's row in LDS

  #pragma unroll 1
  for (int kk = 0; kk < 16; ++kk) {
    float4 cur = xrow[kk];
    const float4* w0 = wr + (kk * 4 + 0) * 16;
    const float4* w1 = wr + (kk * 4 + 1) * 16;
    const float4* w2 = wr + (kk * 4 + 2) * 16;
    const float4* w3 = wr + (kk * 4 + 3) * 16;
    KSTEP(w0, cur.x)
    KSTEP(w1, cur.y)
    KSTEP(w2, cur.z)
    KSTEP(w3, cur.w)
  }

  TANH4(A0)  TANH4(A1)  TANH4(A2)  TANH4(A3)
  TANH4(A4)  TANH4(A5)  TANH4(A6)  TANH4(A7)
  TANH4(A8)  TANH4(A9)  TANH4(A10) TANH4(A11)
  TANH4(A12) TANH4(A13) TANH4(A14) TANH4(A15)

  const float4* kr = (const float4*)keys;    // uniform
  float sim[S];
  #pragma unroll
  for (int s = 0; s < S; ++s) {
    const float4* k4 = kr + s * 16;
    float p = 0.f;
    DOT4ACC(p, A0,  k4[0])  DOT4ACC(p, A1,  k4[1])  DOT4ACC(p, A2,  k4[2])  DOT4ACC(p, A3,  k4[3])
    DOT4ACC(p, A4,  k4[4])  DOT4ACC(p, A5,  k4[5])  DOT4ACC(p, A6,  k4[6])  DOT4ACC(p, A7,  k4[7])
    DOT4ACC(p, A8,  k4[8])  DOT4ACC(p, A9,  k4[9])  DOT4ACC(p, A10, k4[10]) DOT4ACC(p, A11, k4[11])
    DOT4ACC(p, A12, k4[12]) DOT4ACC(p, A13, k4[13]) DOT4ACC(p, A14, k4[14]) DOT4ACC(p, A15, k4[15])
    sim[s] = p;
  }

  float s0 = st4[0], s1 = st4[1], s2 = st4[2], s3 = st4[3];

  float u[S];
  int sel = 0;
  {
    float m = fmaxf(fmaxf(sim[0], sim[1]), fmaxf(sim[2], sim[3]));
    float e0 = expf(sim[0] - m), e1 = expf(sim[1] - m);
    float e2 = expf(sim[2] - m), e3 = expf(sim[3] - m);
    float se = e0 + e1 + e2 + e3;
    float w0 = e0 / se, w1 = e1 / se, w2 = e2 / se, w3 = e3 / se;
    *(float4*)(slot_weights + b * S) = make_float4(w0, w1, w2, w3);
    u[0] = w0 * s0; u[1] = w1 * s1; u[2] = w2 * s2; u[3] = w3 * s3;
    float us = u[0] + u[1] + u[2] + u[3];
    u[0] /= us; u[1] /= us; u[2] /= us; u[3] /= us;
    float best = u[0];
    if (u[1] > best) { best = u[1]; sel = 1; }
    if (u[2] > best) { best = u[2]; sel = 2; }
    if (u[3] > best) { best = u[3]; sel = 3; }
    selected[b] = (float)sel;
  }

  // ---- block reduction: uw sums (add) and last-writer (max) ----
  float r[S]; int l[S];
  #pragma unroll
  for (int s = 0; s < S; ++s) {
    r[s] = u[s];
    l[s] = (sel == s) ? (int)b : -1;
  }
  #pragma unroll
  for (int off = 32; off > 0; off >>= 1) {
    #pragma unroll
    for (int s = 0; s < S; ++s) {
      r[s] += __shfl_down(r[s], off);
      int m = __shfl_down(l[s], off);
      l[s] = l[s] > m ? l[s] : m;
    }
  }
  int lane = t & 63, wid = t >> 6;
  if (lane == 0) {
    #pragma unroll
    for (int s = 0; s < S; ++s) { red_sum[wid][s] = r[s]; red_lw[wid][s] = l[s]; }
  }
  __syncthreads();
  if (t < S) {
    float tot = red_sum[0][t] + red_sum[1][t] + red_sum[2][t] + red_sum[3][t];
    atomicAdd(&red[WS_SUMS + t], tot);
    int lm = red_lw[0][t];
    if (red_lw[1][t] > lm) lm = red_lw[1][t];
    if (red_lw[2][t] > lm) lm = red_lw[2][t];
    if (red_lw[3][t] > lm) lm = red_lw[3][t];
    atomicMax((int*)red + WS_LW + t, lm);
  }
}

__global__ void k_final(const float* __restrict__ item,
                        const float* __restrict__ slots,
                        const float* __restrict__ usage,
                        const float* __restrict__ Wv,
                        const float* __restrict__ bv,
                        float* ws,
                        float* __restrict__ out_ns,
                        float* __restrict__ out_nu,
                        int B) {
  int d = threadIdx.x;  // 64 threads
  __shared__ float mean[D];
  const int* lw = (const int*)ws + WS_LW;
  float nsv[S];
  for (int s = 0; s < S; ++s) {
    int w = lw[s];
    float v = (w >= 0) ? item[(size_t)w * D + d] : slots[s * D + d];
    nsv[s] = v;
    out_ns[s * D + d] = v;
  }
  mean[d] = (nsv[0] + nsv[1] + nsv[2] + nsv[3]) * 0.25f;
  __syncthreads();
  float acc = bv[d];
  for (int k = 0; k < D; ++k) acc = fmaf(mean[k], Wv[d * D + k], acc);
  ws[WS_OUT1 + d] = tanhf(acc);
  if (d < S) out_nu[d] = usage[d] * 0.9f + ws[WS_SUMS + d] / (float)B;
}

__global__ void k_bcast(const float* __restrict__ ws,
                        float4* __restrict__ out, long n4) {
  __shared__ float4 o4[16];
  if (threadIdx.x < 16) o4[threadIdx.x] = ((const float4*)(ws + WS_OUT1))[threadIdx.x];
  __syncthreads();
  long i = (long)blockIdx.x * blockDim.x + threadIdx.x;
  long stride = (long)gridDim.x * blockDim.x;
  for (; i < n4; i += stride) out[i] = o4[i & 15];
}

extern "C" void kernel_launch(void* const* d_in, const int* in_sizes, int n_in,
                              void* d_out, int out_size, void* d_ws, size_t ws_size,
                              hipStream_t stream) {
  const float* item  = (const float*)d_in[0];
  const float* slots = (const float*)d_in[1];
  const float* ss    = (const float*)d_in[2];
  const float* usage = (const float*)d_in[3];
  const float* Wq    = (const float*)d_in[4];
  const float* bq    = (const float*)d_in[5];
  const float* Wk    = (const float*)d_in[6];
  const float* bk    = (const float*)d_in[7];
  const float* Wv    = (const float*)d_in[8];
  const float* bv    = (const float*)d_in[9];
  int B = in_sizes[0] / D;
  float* ws = (float*)d_ws;

  float* out_output       = (float*)d_out;
  float* out_new_slots    = out_output + (size_t)B * D;
  float* out_new_usage    = out_new_slots + S * D;
  float* out_selected     = out_new_usage + S;
  float* out_slot_weights = out_selected + B;

  k_prep<<<1, 64, 0, stream>>>(slots, ss, Wk, bk, Wq, ws);
  k_main<<<(B + 255) / 256, 256, 0, stream>>>(
      item, ws + WS_WQT, ws + WS_KEYS, ws + WS_ST, bq, ws,
      out_slot_weights, out_selected, B);
  k_final<<<1, 64, 0, stream>>>(item, slots, usage, Wv, bv, ws,
                                out_new_slots, out_new_usage, B);
  long n4 = (long)B * D / 4;
  k_bcast<<<2048, 256, 0, stream>>>(ws, (float4*)out_output, n4);
}